// Round 6
// baseline (538.522 us; speedup 1.0000x reference)
//
#include <hip/hip_runtime.h>

#define TOBS  50
#define SDEC  100
#define HID   128
#define EMB   64
#define MD    256
#define M2N   112
#define NZ    16
#define ROWS  32            // 2 independent groups of 16 rows, skewed by one phase
#define KPAD  140           // shorts; 70 dw stride (R2-proven: 4096 conflicts total)
#define H1PAD 268
#define L2E   1.4426950408889634f
#define TL2E  2.8853900817779268f

using bf16x8 = __attribute__((ext_vector_type(8))) short;
using f32x4  = __attribute__((ext_vector_type(4))) float;

struct alignas(16) SMem {
  unsigned short h[2][2][16 * KPAD];     // [group][slot][row*KPAD]  17920 B
  unsigned int offsb[TOBS][ROWS];        // encoder offsets bf16x2    6400 B
  union { unsigned short h1[ROWS * H1PAD]; float4 cl[512]; } u;   // 17152 B
  uint4 b5f[64][5];                      // readout Wr frags, stride 5 = conflict-free
  float offlast[ROWS][2];
  float delta[ROWS][2];
};

__device__ __forceinline__ unsigned int rnd16(float x){
  return __builtin_bit_cast(unsigned int, x) + 0x8000u;
}
__device__ __forceinline__ unsigned int pkbf(float a, float b){
  return __builtin_amdgcn_perm(rnd16(b), rnd16(a), 0x07060302u);
}
__device__ __forceinline__ unsigned short bfs(float x){ return (unsigned short)(rnd16(x) >> 16); }
__device__ __forceinline__ float rcpf(float x){ return __builtin_amdgcn_rcpf(x); }
__device__ __forceinline__ float ex2(float x){ return __builtin_amdgcn_exp2f(x); }
__device__ __forceinline__ bf16x8 pack8(const float* p){
  float4 a = *(const float4*)p;
  float4 b = *(const float4*)(p + 4);
  uint4 u;
  u.x = pkbf(a.x, a.y); u.y = pkbf(a.z, a.w);
  u.z = pkbf(b.x, b.y); u.w = pkbf(b.z, b.w);
  return __builtin_bit_cast(bf16x8, u);
}

// ---- phase building blocks (macros so register arrays stay statically indexed) ----
#define ENC_MFMA(G, T, ACC) do { \
  const unsigned short* hb_ = &sm.h[G][((T) & 1) ^ 1][0]; \
  bf16x8 af_[4]; \
  _Pragma("unroll") for (int kt_ = 0; kt_ < 4; ++kt_) \
    af_[kt_] = *(const bf16x8*)&hb_[cc*KPAD + kt_*32 + qd*8]; \
  unsigned int po_ = sm.offsb[T][(G)*16 + cc]; \
  uint4 a5i_; a5i_.x = q0 ? po_ : 0u; a5i_.y = one_q0; a5i_.z = 0u; a5i_.w = 0u; \
  bf16x8 af5_ = __builtin_bit_cast(bf16x8, a5i_); \
  _Pragma("unroll") for (int g_ = 0; g_ < 4; ++g_) \
    ACC[g_] = __builtin_amdgcn_mfma_f32_16x16x32_bf16(af5_, b5x[g_], zz4, 0,0,0); \
  _Pragma("unroll") for (int kt_ = 0; kt_ < 4; ++kt_) \
    _Pragma("unroll") for (int g_ = 0; g_ < 4; ++g_) \
      ACC[g_] = __builtin_amdgcn_mfma_f32_16x16x32_bf16(af_[kt_], bfr[g_][kt_], ACC[g_], 0,0,0); \
} while(0)

#define DEC_MFMA(G, S, ACC, AF5, CUM) do { \
  const unsigned short* hb_ = &sm.h[G][((S) & 1) ^ 1][0]; \
  bf16x8 af_[4]; \
  _Pragma("unroll") for (int kt_ = 0; kt_ < 4; ++kt_) \
    af_[kt_] = *(const bf16x8*)&hb_[cc*KPAD + kt_*32 + qd*8]; \
  _Pragma("unroll") for (int g_ = 0; g_ < 4; ++g_) \
    ACC[g_] = __builtin_amdgcn_mfma_f32_16x16x32_bf16(AF5, b5x[g_], zz4, 0,0,0); \
  _Pragma("unroll") for (int kt_ = 0; kt_ < 4; ++kt_) \
    _Pragma("unroll") for (int g_ = 0; g_ < 4; ++g_) \
      ACC[g_] = __builtin_amdgcn_mfma_f32_16x16x32_bf16(af_[kt_], bfr[g_][kt_], ACC[g_], 0,0,0); \
  if (jq == 1 && (S) > 0){ \
    f32x4 a5_ = {brc, brc, brc, brc}; \
    _Pragma("unroll") for (int kt_ = 0; kt_ < 4; ++kt_) \
      a5_ = __builtin_amdgcn_mfma_f32_16x16x32_bf16(af_[kt_], \
              __builtin_bit_cast(bf16x8, sm.b5f[lane][kt_]), a5_, 0,0,0); \
    if (cc < 2){ \
      _Pragma("unroll") for (int r_ = 0; r_ < 4; ++r_){ \
        CUM[r_] += a5_[r_]; \
        out[((size_t)(R0 + (G)*16 + qd*4 + r_)*SDEC + ((S)-1))*2 + cc] = CUM[r_]; \
      } \
    } \
  } \
} while(0)

#define ELEM(G, T, ACC, CST) do { \
  unsigned short* hn_ = &sm.h[G][(T) & 1][0]; \
  _Pragma("unroll") for (int r_ = 0; r_ < 4; ++r_){ \
    float iv_ = ACC[0][r_], fv_ = ACC[1][r_], gv_ = ACC[2][r_], ov_ = ACC[3][r_]; \
    float ef_ = ex2(-fv_ * L2E); \
    float sf_ = rcpf(1.0f + ef_); \
    float ei_ = ex2(-iv_ * L2E); \
    float eg_ = ex2(-gv_ * TL2E); \
    float ig_ = (1.0f - eg_) * rcpf((1.0f + ei_) * (1.0f + eg_)); \
    float cn_ = sf_ * CST[r_] + ig_; CST[r_] = cn_; \
    float eo_ = ex2(-ov_ * L2E); \
    float ec_ = ex2(-cn_ * TL2E); \
    float hh_ = (1.0f - ec_) * rcpf((1.0f + eo_) * (1.0f + ec_)); \
    hn_[(qd*4 + r_)*KPAD + colj] = bfs(hh_); \
  } \
} while(0)

extern "C" __global__ void __launch_bounds__(512, 2)
seqgen(const float* __restrict__ obs,
       const float* __restrict__ We,    const float* __restrict__ be,
       const float* __restrict__ Wih_e, const float* __restrict__ Whh_e, const float* __restrict__ b_e,
       const float* __restrict__ Wm1,   const float* __restrict__ bm1,
       const float* __restrict__ Wm2,   const float* __restrict__ bm2,
       const float* __restrict__ Wd,    const float* __restrict__ bd,
       const float* __restrict__ Wih_d, const float* __restrict__ Whh_d, const float* __restrict__ b_d,
       const float* __restrict__ Wr,    const float* __restrict__ br,
       const float* __restrict__ z,     float* __restrict__ out)
{
  __shared__ SMem sm;
  const int tid  = threadIdx.x;
  const int lane = tid & 63;
  const int jq   = tid >> 6;        // wave = column tile 0..7
  const int cc   = lane & 15;
  const int qd   = lane >> 4;
  const bool q0  = (qd == 0);
  const int R0   = blockIdx.x * ROWS;
  const int colj = jq * 16 + cc;
  const unsigned int one_q0 = q0 ? 0x3F80u : 0u;

  // ---------------- prep ----------------
  for (int i = tid; i < TOBS * ROWS; i += 512){
    int t = i >> 5, row = i & 31;
    const float* ob = obs + (size_t)(R0 + row) * (TOBS * 2) + t * 2;
    float o0 = ob[0], o1 = ob[1];
    if (t){ o0 -= ob[-2]; o1 -= ob[-1]; }
    sm.offsb[t][row] = pkbf(o0, o1);
    if (t == TOBS - 1){ sm.offlast[row][0] = o0; sm.offlast[row][1] = o1; }
  }
  for (int i = tid; i < 16 * KPAD / 2; i += 512){   // zero h[g][1] (initial state)
    ((unsigned int*)&sm.h[0][1][0])[i] = 0u;
    ((unsigned int*)&sm.h[1][1][0])[i] = 0u;
  }
  {
    const float* wr = Wih_e + tid * EMB;
    float w0 = 0.f, w1 = 0.f, bb = b_e[tid];
    for (int e = 0; e < EMB; ++e){
      float w = wr[e];
      w0 += w * We[e*2]; w1 += w * We[e*2+1]; bb += w * be[e];
    }
    sm.u.cl[tid] = make_float4(bb, w0, w1, 0.f);
  }
  __syncthreads();

  // input/bias B-fragments {w0,w1,bc} (k=0,1,2) for 4 gates
  bf16x8 b5x[4];
  #pragma unroll
  for (int g = 0; g < 4; ++g){
    float4 v = sm.u.cl[g*128 + colj];
    uint4 w;
    w.x = q0 ? pkbf(v.y, v.z) : 0u;
    w.y = q0 ? (rnd16(v.x) >> 16) : 0u;
    w.z = 0u; w.w = 0u;
    b5x[g] = __builtin_bit_cast(bf16x8, w);
  }
  // encoder Whh in registers (4 gates x 4 k-tiles)
  bf16x8 bfr[4][4];
  #pragma unroll
  for (int kt = 0; kt < 4; ++kt)
    #pragma unroll
    for (int g = 0; g < 4; ++g)
      bfr[g][kt] = pack8(Whh_e + (size_t)(g*128 + colj) * HID + kt*32 + qd*8);

  const f32x4 zz4 = {0.f, 0.f, 0.f, 0.f};
  f32x4 acc0[4], acc1[4];
  float cst0[4] = {0.f,0.f,0.f,0.f}, cst1[4] = {0.f,0.f,0.f,0.f};

  // ================= encoder: 2*TOBS+1 skewed phases =================
  ENC_MFMA(0, 0, acc0);
  __syncthreads();
  ENC_MFMA(1, 0, acc1); ELEM(0, 0, acc0, cst0);
  __syncthreads();
  #pragma unroll 1
  for (int t = 1; t < TOBS; ++t){
    ENC_MFMA(0, t, acc0); ELEM(1, t-1, acc1, cst1);
    __syncthreads();
    ENC_MFMA(1, t, acc1); ELEM(0, t, acc0, cst0);
    __syncthreads();
  }
  ELEM(1, TOBS-1, acc1, cst1);
  __syncthreads();
  // hF in sm.h[g][1]

  // ================= MLP =================
  {
    bf16x8 af[2][4];
    #pragma unroll
    for (int rg = 0; rg < 2; ++rg)
      #pragma unroll
      for (int kt = 0; kt < 4; ++kt)
        af[rg][kt] = *(const bf16x8*)&sm.h[rg][1][cc*KPAD + kt*32 + qd*8];
    f32x4 a1[2][2];
    #pragma unroll
    for (int t2 = 0; t2 < 2; ++t2){
      const int n = jq*32 + t2*16 + cc;
      float b = bm1[n];
      #pragma unroll
      for (int rg = 0; rg < 2; ++rg){ a1[t2][rg][0]=b; a1[t2][rg][1]=b; a1[t2][rg][2]=b; a1[t2][rg][3]=b; }
      #pragma unroll
      for (int kt = 0; kt < 4; ++kt){
        bf16x8 wb = pack8(Wm1 + (size_t)n * HID + kt*32 + qd*8);
        a1[t2][0] = __builtin_amdgcn_mfma_f32_16x16x32_bf16(af[0][kt], wb, a1[t2][0], 0,0,0);
        a1[t2][1] = __builtin_amdgcn_mfma_f32_16x16x32_bf16(af[1][kt], wb, a1[t2][1], 0,0,0);
      }
    }
    #pragma unroll
    for (int t2 = 0; t2 < 2; ++t2)
      #pragma unroll
      for (int rg = 0; rg < 2; ++rg)
        #pragma unroll
        for (int r = 0; r < 4; ++r){
          float v = a1[t2][rg][r]; v = v > 0.f ? v : 0.f;
          sm.u.h1[(rg*16 + qd*4 + r)*H1PAD + jq*32 + t2*16 + cc] = bfs(v);
        }
  }
  __syncthreads();
  {
    bf16x8 af2[2][8];
    #pragma unroll
    for (int rg = 0; rg < 2; ++rg)
      #pragma unroll
      for (int kt = 0; kt < 8; ++kt)
        af2[rg][kt] = *(const bf16x8*)&sm.u.h1[(rg*16 + cc)*H1PAD + kt*32 + qd*8];
    if (jq < 7){
      const int n2 = jq*16 + cc;
      float b = bm2[n2];
      f32x4 a2[2];
      #pragma unroll
      for (int rg = 0; rg < 2; ++rg){ a2[rg][0]=b; a2[rg][1]=b; a2[rg][2]=b; a2[rg][3]=b; }
      #pragma unroll
      for (int kt = 0; kt < 8; ++kt){
        bf16x8 wb = pack8(Wm2 + (size_t)n2 * MD + kt*32 + qd*8);
        a2[0] = __builtin_amdgcn_mfma_f32_16x16x32_bf16(af2[0][kt], wb, a2[0], 0,0,0);
        a2[1] = __builtin_amdgcn_mfma_f32_16x16x32_bf16(af2[1][kt], wb, a2[1], 0,0,0);
      }
      #pragma unroll
      for (int rg = 0; rg < 2; ++rg)
        #pragma unroll
        for (int r = 0; r < 4; ++r){
          float v = a2[rg][r]; v = v > 0.f ? v : 0.f;
          sm.h[rg][1][(qd*4 + r)*KPAD + jq*16 + cc] = bfs(v);
        }
    }
    {  // z concat (tid covers all 32x16)
      int row = tid >> 4, nz = tid & 15;
      sm.h[row >> 4][1][(row & 15)*KPAD + M2N + nz] = bfs(z[(size_t)(R0 + row)*NZ + nz]);
    }
  }
  __syncthreads();   // dh complete in h[g][1]; u region reusable

  // ================= decoder prep =================
  {
    const float* wr = Wih_d + tid * EMB;
    float w0 = 0.f, w1 = 0.f, bb = b_d[tid];
    for (int e = 0; e < EMB; ++e){
      float w = wr[e];
      w0 += w * Wd[e*2]; w1 += w * Wd[e*2+1]; bb += w * bd[e];
    }
    sm.u.cl[tid] = make_float4(bb, w0, w1, 0.f);
  }
  const float br0 = br[0], br1 = br[1];
  const float brc = (cc == 0) ? br0 : br1;
  if (jq == 1){   // Wr readout fragments + step-0 delta for both groups
    uint4 bq[4];
    #pragma unroll
    for (int kt = 0; kt < 4; ++kt){
      bf16x8 f = pack8(Wr + (size_t)(cc & 1)*HID + kt*32 + qd*8);
      uint4 uu = __builtin_bit_cast(uint4, f);
      if (cc >= 2){ uu.x = 0u; uu.y = 0u; uu.z = 0u; uu.w = 0u; }
      bq[kt] = uu;
      sm.b5f[lane][kt] = uu;
    }
    #pragma unroll
    for (int G = 0; G < 2; ++G){
      bf16x8 afd[4];
      #pragma unroll
      for (int kt = 0; kt < 4; ++kt)
        afd[kt] = *(const bf16x8*)&sm.h[G][1][cc*KPAD + kt*32 + qd*8];
      f32x4 a5 = zz4;
      #pragma unroll
      for (int kt = 0; kt < 4; ++kt)
        a5 = __builtin_amdgcn_mfma_f32_16x16x32_bf16(afd[kt], __builtin_bit_cast(bf16x8, bq[kt]), a5, 0,0,0);
      if (cc < 2){
        #pragma unroll
        for (int r = 0; r < 4; ++r){
          int row = G*16 + qd*4 + r;
          sm.delta[row][cc] = sm.offlast[row][cc] - (a5[r] + brc);
        }
      }
    }
  }
  __syncthreads();

  // feedback-folded decoder consts: b5x' and bfr' = Whh_d + u0(x)Wr0 + u1(x)Wr1
  float w0g[4], w1g[4];
  #pragma unroll
  for (int g = 0; g < 4; ++g){
    float4 v = sm.u.cl[g*128 + colj];
    w0g[g] = v.y; w1g[g] = v.z;
    float bcp = v.x + v.y*br0 + v.z*br1;
    uint4 w;
    w.x = q0 ? pkbf(v.y, v.z) : 0u;
    w.y = q0 ? (rnd16(bcp) >> 16) : 0u;
    w.z = 0u; w.w = 0u;
    b5x[g] = __builtin_bit_cast(bf16x8, w);
  }
  #pragma unroll
  for (int kt = 0; kt < 4; ++kt){
    const int kb = kt*32 + qd*8;
    float4 wa = *(const float4*)(Wr + kb),       wb2 = *(const float4*)(Wr + kb + 4);
    float4 va = *(const float4*)(Wr + HID + kb), vb2 = *(const float4*)(Wr + HID + kb + 4);
    #pragma unroll
    for (int g = 0; g < 4; ++g){
      const float* pp = Whh_d + (size_t)(g*128 + colj) * HID + kb;
      float4 fa = *(const float4*)pp, fb = *(const float4*)(pp + 4);
      uint4 uu;
      uu.x = pkbf(fa.x + w0g[g]*wa.x  + w1g[g]*va.x,  fa.y + w0g[g]*wa.y  + w1g[g]*va.y);
      uu.y = pkbf(fa.z + w0g[g]*wa.z  + w1g[g]*va.z,  fa.w + w0g[g]*wa.w  + w1g[g]*va.w);
      uu.z = pkbf(fb.x + w0g[g]*wb2.x + w1g[g]*vb2.x, fb.y + w0g[g]*wb2.y + w1g[g]*vb2.y);
      uu.w = pkbf(fb.z + w0g[g]*wb2.z + w1g[g]*vb2.z, fb.w + w0g[g]*wb2.w + w1g[g]*vb2.w);
      bfr[g][kt] = __builtin_bit_cast(bf16x8, uu);
    }
  }
  // step-0 delta A-fragments + steady {0,0,1}
  uint4 c5; c5.x = 0u; c5.y = one_q0; c5.z = 0u; c5.w = 0u;
  const bf16x8 af5c = __builtin_bit_cast(bf16x8, c5);
  float2 dv0 = *(const float2*)&sm.delta[cc][0];
  float2 dv1 = *(const float2*)&sm.delta[16 + cc][0];
  uint4 d0u = c5; d0u.x = q0 ? pkbf(dv0.x, dv0.y) : 0u;
  uint4 d1u = c5; d1u.x = q0 ? pkbf(dv1.x, dv1.y) : 0u;
  const bf16x8 af5d0 = __builtin_bit_cast(bf16x8, d0u);
  const bf16x8 af5d1 = __builtin_bit_cast(bf16x8, d1u);

  float cum0[4] = {0.f,0.f,0.f,0.f}, cum1[4] = {0.f,0.f,0.f,0.f};
  if (jq == 1 && cc < 2){
    #pragma unroll
    for (int r = 0; r < 4; ++r){
      cum0[r] = obs[(size_t)(R0 + qd*4 + r)*(TOBS*2) + (TOBS-1)*2 + cc];
      cum1[r] = obs[(size_t)(R0 + 16 + qd*4 + r)*(TOBS*2) + (TOBS-1)*2 + cc];
    }
  }
  #pragma unroll
  for (int r = 0; r < 4; ++r){ cst0[r] = 0.f; cst1[r] = 0.f; }
  __syncthreads();

  // ================= decoder: 2*SDEC+1 skewed phases =================
  DEC_MFMA(0, 0, acc0, af5d0, cum0);
  __syncthreads();
  DEC_MFMA(1, 0, acc1, af5d1, cum1); ELEM(0, 0, acc0, cst0);
  __syncthreads();
  #pragma unroll 1
  for (int s = 1; s < SDEC; ++s){
    DEC_MFMA(0, s, acc0, af5c, cum0); ELEM(1, s-1, acc1, cst1);
    __syncthreads();
    DEC_MFMA(1, s, acc1, af5c, cum1); ELEM(0, s, acc0, cst0);
    __syncthreads();
  }
  ELEM(1, SDEC-1, acc1, cst1);
  __syncthreads();

  // epilogue: pred[S-1] for both groups from h[g][1]
  if (jq == 1){
    #pragma unroll
    for (int G = 0; G < 2; ++G){
      bf16x8 af[4];
      #pragma unroll
      for (int kt = 0; kt < 4; ++kt)
        af[kt] = *(const bf16x8*)&sm.h[G][1][cc*KPAD + kt*32 + qd*8];
      f32x4 a5 = {brc, brc, brc, brc};
      #pragma unroll
      for (int kt = 0; kt < 4; ++kt)
        a5 = __builtin_amdgcn_mfma_f32_16x16x32_bf16(af[kt],
               __builtin_bit_cast(bf16x8, sm.b5f[lane][kt]), a5, 0,0,0);
      if (cc < 2){
        #pragma unroll
        for (int r = 0; r < 4; ++r){
          float cv = (G == 0 ? cum0[r] : cum1[r]) + a5[r];
          out[((size_t)(R0 + G*16 + qd*4 + r)*SDEC + (SDEC-1))*2 + cc] = cv;
        }
      }
    }
  }
}

extern "C" void kernel_launch(void* const* d_in, const int* in_sizes, int n_in,
                              void* d_out, int out_size, void* d_ws, size_t ws_size,
                              hipStream_t stream) {
  (void)in_sizes; (void)n_in; (void)d_ws; (void)ws_size; (void)out_size;
  const float* obs   = (const float*)d_in[0];
  // d_in[1] = num_steps (100), compile-time constant here
  const float* We    = (const float*)d_in[2];
  const float* be    = (const float*)d_in[3];
  const float* Wih_e = (const float*)d_in[4];
  const float* Whh_e = (const float*)d_in[5];
  const float* b_e   = (const float*)d_in[6];
  const float* Wm1   = (const float*)d_in[7];
  const float* bm1   = (const float*)d_in[8];
  const float* Wm2   = (const float*)d_in[9];
  const float* bm2   = (const float*)d_in[10];
  const float* Wd    = (const float*)d_in[11];
  const float* bd    = (const float*)d_in[12];
  const float* Wih_d = (const float*)d_in[13];
  const float* Whh_d = (const float*)d_in[14];
  const float* b_d   = (const float*)d_in[15];
  const float* Wr    = (const float*)d_in[16];
  const float* br    = (const float*)d_in[17];
  const float* zz    = (const float*)d_in[18];
  hipLaunchKernelGGL(seqgen, dim3(8192 / ROWS), dim3(512), 0, stream,
                     obs, We, be, Wih_e, Whh_e, b_e, Wm1, bm1, Wm2, bm2,
                     Wd, bd, Wih_d, Whh_d, b_d, Wr, br, zz, (float*)d_out);
}

// Round 7
// 342.986 us; speedup vs baseline: 1.5701x; 1.5701x over previous
//
#include <hip/hip_runtime.h>

#define TOBS  50
#define SDEC  100
#define HID   128
#define EMB   64
#define MD    256
#define M2N   112
#define NZ    16
#define ROWS  32
#define KPAD  140           // shorts; 70-dw row stride (R2-proven low-conflict)
#define H1PAD 268
#define L2E   1.4426950408889634f
#define TL2E  2.8853900817779268f

using bf16x8 = __attribute__((ext_vector_type(8))) short;
using f32x4  = __attribute__((ext_vector_type(4))) float;

struct alignas(16) SMem {
  unsigned short h[2][ROWS * KPAD];      // 17920 B  h double buffer (bf16)
  unsigned int offsb[TOBS][ROWS];        //  6400 B  encoder offsets (bf16x2)
  union {
    float4 cl[512];                      //  8192 B  fused input consts
    unsigned short h1[ROWS * H1PAD];     // 17152 B  MLP hidden
    float outst[ROWS][SDEC][2];          // 25600 B  decoder output staging
  } u;
  uint4 b5f[64][5];                      //  5120 B  readout Wr frags (stride 5)
  float offlast[ROWS][2];
  float delta[ROWS][2];
};

__device__ __forceinline__ unsigned int rnd16(float x){
  return __builtin_bit_cast(unsigned int, x) + 0x8000u;
}
__device__ __forceinline__ unsigned int pkbf(float a, float b){
  return __builtin_amdgcn_perm(rnd16(b), rnd16(a), 0x07060302u);
}
__device__ __forceinline__ unsigned short bfs(float x){ return (unsigned short)(rnd16(x) >> 16); }
__device__ __forceinline__ float rcpf(float x){ return __builtin_amdgcn_rcpf(x); }
__device__ __forceinline__ float ex2(float x){ return __builtin_amdgcn_exp2f(x); }
__device__ __forceinline__ bf16x8 pack8s(const float* p, float s){
  float4 a = *(const float4*)p;
  float4 b = *(const float4*)(p + 4);
  uint4 u;
  u.x = pkbf(s*a.x, s*a.y); u.y = pkbf(s*a.z, s*a.w);
  u.z = pkbf(s*b.x, s*b.y); u.w = pkbf(s*b.z, s*b.w);
  return __builtin_bit_cast(bf16x8, u);
}
__device__ __forceinline__ bf16x8 pack8(const float* p){ return pack8s(p, 1.0f); }

extern "C" __global__ void __launch_bounds__(512, 2)
seqgen(const float* __restrict__ obs,
       const float* __restrict__ We,    const float* __restrict__ be,
       const float* __restrict__ Wih_e, const float* __restrict__ Whh_e, const float* __restrict__ b_e,
       const float* __restrict__ Wm1,   const float* __restrict__ bm1,
       const float* __restrict__ Wm2,   const float* __restrict__ bm2,
       const float* __restrict__ Wd,    const float* __restrict__ bd,
       const float* __restrict__ Wih_d, const float* __restrict__ Whh_d, const float* __restrict__ b_d,
       const float* __restrict__ Wr,    const float* __restrict__ br,
       const float* __restrict__ z,     float* __restrict__ out)
{
  __shared__ SMem sm;
  const int tid  = threadIdx.x;
  const int lane = tid & 63;
  const int jq   = tid >> 6;        // wave = 16-col tile (0..7)
  const int cc   = lane & 15;
  const int qd   = lane >> 4;
  const bool q0  = (qd == 0);
  const int R0   = blockIdx.x * ROWS;
  const int colj = jq * 16 + cc;
  const unsigned int one_q0 = q0 ? 0x3F80u : 0u;
  const float sg4[4] = {-L2E, -L2E, -TL2E, -L2E};   // exp2 scale folded per gate

  // ---------------- prep ----------------
  for (int i = tid; i < TOBS * ROWS; i += 512){
    int t = i >> 5, row = i & 31;
    const float* ob = obs + (size_t)(R0 + row) * (TOBS * 2) + t * 2;
    float o0 = ob[0], o1 = ob[1];
    if (t){ o0 -= ob[-2]; o1 -= ob[-1]; }
    sm.offsb[t][row] = pkbf(o0, o1);
    if (t == TOBS - 1){ sm.offlast[row][0] = o0; sm.offlast[row][1] = o1; }
  }
  for (int i = tid; i < ROWS * KPAD / 2; i += 512)
    ((unsigned int*)&sm.h[0][0])[i] = 0u;
  {
    const float* wr = Wih_e + tid * EMB;
    float w0 = 0.f, w1 = 0.f, bb = b_e[tid];
    for (int e = 0; e < EMB; ++e){
      float w = wr[e];
      w0 += w * We[e*2]; w1 += w * We[e*2+1]; bb += w * be[e];
    }
    sm.u.cl[tid] = make_float4(bb, w0, w1, 0.f);
  }
  __syncthreads();

  // input/bias B-frags {s*w0, s*w1, s*bc} at k=0,1,2 (qd==0 lanes)
  bf16x8 b5x[4];
  #pragma unroll
  for (int g = 0; g < 4; ++g){
    float4 v = sm.u.cl[g*128 + colj];
    float s = sg4[g];
    uint4 w;
    w.x = q0 ? pkbf(s*v.y, s*v.z) : 0u;
    w.y = q0 ? (rnd16(s*v.x) >> 16) : 0u;
    w.z = 0u; w.w = 0u;
    b5x[g] = __builtin_bit_cast(bf16x8, w);
  }
  // encoder Whh in registers, pre-scaled per gate
  bf16x8 bfr[4][4];
  #pragma unroll
  for (int kt = 0; kt < 4; ++kt)
    #pragma unroll
    for (int g = 0; g < 4; ++g)
      bfr[g][kt] = pack8s(Whh_e + (size_t)(g*128 + colj) * HID + kt*32 + qd*8, sg4[g]);

  const f32x4 zz4 = {0.f, 0.f, 0.f, 0.f};
  f32x4 acc[2][4];
  float cst[2][4];
  #pragma unroll
  for (int G = 0; G < 2; ++G)
    #pragma unroll
    for (int r = 0; r < 4; ++r) cst[G][r] = 0.f;

  // ================= encoder: 50 steps, ONE barrier/step =================
  #pragma unroll 1
  for (int t = 0; t < TOBS; ++t){
    const int par = t & 1;
    bf16x8 af[2][4];
    #pragma unroll
    for (int G = 0; G < 2; ++G)
      #pragma unroll
      for (int kt = 0; kt < 4; ++kt)
        af[G][kt] = *(const bf16x8*)&sm.h[par][(G*16 + cc)*KPAD + kt*32 + qd*8];
    #pragma unroll
    for (int G = 0; G < 2; ++G){
      unsigned int po = sm.offsb[t][G*16 + cc];
      uint4 a5i; a5i.x = q0 ? po : 0u; a5i.y = one_q0; a5i.z = 0u; a5i.w = 0u;
      bf16x8 af5 = __builtin_bit_cast(bf16x8, a5i);
      #pragma unroll
      for (int g = 0; g < 4; ++g)
        acc[G][g] = __builtin_amdgcn_mfma_f32_16x16x32_bf16(af5, b5x[g], zz4, 0,0,0);
    }
    #pragma unroll
    for (int kt = 0; kt < 4; ++kt)
      #pragma unroll
      for (int G = 0; G < 2; ++G)
        #pragma unroll
        for (int g = 0; g < 4; ++g)
          acc[G][g] = __builtin_amdgcn_mfma_f32_16x16x32_bf16(af[G][kt], bfr[g][kt], acc[G][g], 0,0,0);

    unsigned short* hn = &sm.h[par ^ 1][0];
    #pragma unroll
    for (int G = 0; G < 2; ++G)
      #pragma unroll
      for (int r = 0; r < 4; ++r){
        float ei = ex2(acc[G][0][r]), ef = ex2(acc[G][1][r]);
        float eg = ex2(acc[G][2][r]), eo = ex2(acc[G][3][r]);
        float a1 = 1.0f + ef, a2 = 1.0f + ei, a3 = 1.0f + eg;
        float P  = a2 * a3;
        float rD = rcpf(a1 * P);
        float N  = __builtin_fmaf(cst[G][r], P, (1.0f - eg) * a1);
        float cn = N * rD;
        cst[G][r] = cn;
        float em = ex2(cn * (-TL2E));
        float rQ = rcpf((1.0f + eo) * (1.0f + em));
        float hh = (1.0f - em) * rQ;
        hn[(G*16 + qd*4 + r)*KPAD + colj] = bfs(hh);
      }
    __syncthreads();
  }
  // hF in sm.h[0]

  // ================= MLP =================
  {
    bf16x8 af[2][4];
    #pragma unroll
    for (int G = 0; G < 2; ++G)
      #pragma unroll
      for (int kt = 0; kt < 4; ++kt)
        af[G][kt] = *(const bf16x8*)&sm.h[0][(G*16 + cc)*KPAD + kt*32 + qd*8];
    f32x4 a1[2][2];
    #pragma unroll
    for (int t2 = 0; t2 < 2; ++t2){
      const int n = jq*32 + t2*16 + cc;
      float b = bm1[n];
      #pragma unroll
      for (int G = 0; G < 2; ++G){ a1[t2][G][0]=b; a1[t2][G][1]=b; a1[t2][G][2]=b; a1[t2][G][3]=b; }
      #pragma unroll
      for (int kt = 0; kt < 4; ++kt){
        bf16x8 wb = pack8(Wm1 + (size_t)n * HID + kt*32 + qd*8);
        a1[t2][0] = __builtin_amdgcn_mfma_f32_16x16x32_bf16(af[0][kt], wb, a1[t2][0], 0,0,0);
        a1[t2][1] = __builtin_amdgcn_mfma_f32_16x16x32_bf16(af[1][kt], wb, a1[t2][1], 0,0,0);
      }
    }
    __syncthreads();   // h[0] reads done (cl reads long done)
    #pragma unroll
    for (int t2 = 0; t2 < 2; ++t2)
      #pragma unroll
      for (int G = 0; G < 2; ++G)
        #pragma unroll
        for (int r = 0; r < 4; ++r){
          float v = a1[t2][G][r]; v = v > 0.f ? v : 0.f;
          sm.u.h1[(G*16 + qd*4 + r)*H1PAD + jq*32 + t2*16 + cc] = bfs(v);
        }
  }
  __syncthreads();
  {
    bf16x8 af2[2][8];
    #pragma unroll
    for (int G = 0; G < 2; ++G)
      #pragma unroll
      for (int kt = 0; kt < 8; ++kt)
        af2[G][kt] = *(const bf16x8*)&sm.u.h1[(G*16 + cc)*H1PAD + kt*32 + qd*8];
    if (jq < 7){
      const int n2 = jq*16 + cc;
      float b = bm2[n2];
      f32x4 a2[2];
      #pragma unroll
      for (int G = 0; G < 2; ++G){ a2[G][0]=b; a2[G][1]=b; a2[G][2]=b; a2[G][3]=b; }
      #pragma unroll
      for (int kt = 0; kt < 8; ++kt){
        bf16x8 wb = pack8(Wm2 + (size_t)n2 * MD + kt*32 + qd*8);
        a2[0] = __builtin_amdgcn_mfma_f32_16x16x32_bf16(af2[0][kt], wb, a2[0], 0,0,0);
        a2[1] = __builtin_amdgcn_mfma_f32_16x16x32_bf16(af2[1][kt], wb, a2[1], 0,0,0);
      }
      #pragma unroll
      for (int G = 0; G < 2; ++G)
        #pragma unroll
        for (int r = 0; r < 4; ++r){
          float v = a2[G][r]; v = v > 0.f ? v : 0.f;
          sm.h[0][(G*16 + qd*4 + r)*KPAD + n2] = bfs(v);
        }
    }
    {
      int row = tid >> 4, nz = tid & 15;
      sm.h[0][row*KPAD + M2N + nz] = bfs(z[(size_t)(R0 + row)*NZ + nz]);
    }
  }
  __syncthreads();   // dh complete in h[0]

  // ================= decoder prep =================
  {
    const float* wr = Wih_d + tid * EMB;
    float w0 = 0.f, w1 = 0.f, bb = b_d[tid];
    for (int e = 0; e < EMB; ++e){
      float w = wr[e];
      w0 += w * Wd[e*2]; w1 += w * Wd[e*2+1]; bb += w * bd[e];
    }
    sm.u.cl[tid] = make_float4(bb, w0, w1, 0.f);
  }
  const float br0 = br[0], br1 = br[1];
  const float brc = (cc == 0) ? br0 : br1;
  if (jq == 1){   // readout Wr fragments + step-0 delta
    uint4 bq[4];
    #pragma unroll
    for (int kt = 0; kt < 4; ++kt){
      bf16x8 f = pack8(Wr + (size_t)(cc & 1)*HID + kt*32 + qd*8);
      uint4 uu = __builtin_bit_cast(uint4, f);
      if (cc >= 2){ uu.x = 0u; uu.y = 0u; uu.z = 0u; uu.w = 0u; }
      bq[kt] = uu;
      sm.b5f[lane][kt] = uu;
    }
    #pragma unroll
    for (int G = 0; G < 2; ++G){
      bf16x8 afd[4];
      #pragma unroll
      for (int kt = 0; kt < 4; ++kt)
        afd[kt] = *(const bf16x8*)&sm.h[0][(G*16 + cc)*KPAD + kt*32 + qd*8];
      f32x4 a5 = zz4;
      #pragma unroll
      for (int kt = 0; kt < 4; ++kt)
        a5 = __builtin_amdgcn_mfma_f32_16x16x32_bf16(afd[kt], __builtin_bit_cast(bf16x8, bq[kt]), a5, 0,0,0);
      if (cc < 2){
        #pragma unroll
        for (int r = 0; r < 4; ++r){
          int row = G*16 + qd*4 + r;
          sm.delta[row][cc] = sm.offlast[row][cc] - (a5[r] + brc);
        }
      }
    }
  }
  __syncthreads();

  // feedback-folded decoder consts (pre-scaled): bfr' = s_g*(Whh_d + u0(x)Wr0 + u1(x)Wr1)
  float w0g[4], w1g[4];
  #pragma unroll
  for (int g = 0; g < 4; ++g){
    float4 v = sm.u.cl[g*128 + colj];
    w0g[g] = v.y; w1g[g] = v.z;
    float s = sg4[g];
    float bcp = v.x + v.y*br0 + v.z*br1;
    uint4 w;
    w.x = q0 ? pkbf(s*v.y, s*v.z) : 0u;
    w.y = q0 ? (rnd16(s*bcp) >> 16) : 0u;
    w.z = 0u; w.w = 0u;
    b5x[g] = __builtin_bit_cast(bf16x8, w);
  }
  #pragma unroll
  for (int kt = 0; kt < 4; ++kt){
    const int kb = kt*32 + qd*8;
    float4 wa = *(const float4*)(Wr + kb),       wb2 = *(const float4*)(Wr + kb + 4);
    float4 va = *(const float4*)(Wr + HID + kb), vb2 = *(const float4*)(Wr + HID + kb + 4);
    #pragma unroll
    for (int g = 0; g < 4; ++g){
      const float* pp = Whh_d + (size_t)(g*128 + colj) * HID + kb;
      float4 fa = *(const float4*)pp, fb = *(const float4*)(pp + 4);
      float s = sg4[g];
      uint4 uu;
      uu.x = pkbf(s*(fa.x + w0g[g]*wa.x  + w1g[g]*va.x),  s*(fa.y + w0g[g]*wa.y  + w1g[g]*va.y));
      uu.y = pkbf(s*(fa.z + w0g[g]*wa.z  + w1g[g]*va.z),  s*(fa.w + w0g[g]*wa.w  + w1g[g]*va.w));
      uu.z = pkbf(s*(fb.x + w0g[g]*wb2.x + w1g[g]*vb2.x), s*(fb.y + w0g[g]*wb2.y + w1g[g]*vb2.y));
      uu.w = pkbf(s*(fb.z + w0g[g]*wb2.z + w1g[g]*vb2.z), s*(fb.w + w0g[g]*wb2.w + w1g[g]*vb2.w));
      bfr[g][kt] = __builtin_bit_cast(bf16x8, uu);
    }
  }
  // step-0 delta A-frags + steady {0,0,1}
  uint4 c5; c5.x = 0u; c5.y = one_q0; c5.z = 0u; c5.w = 0u;
  const bf16x8 af5c = __builtin_bit_cast(bf16x8, c5);
  float2 dv0 = *(const float2*)&sm.delta[cc][0];
  float2 dv1 = *(const float2*)&sm.delta[16 + cc][0];
  uint4 d0u = c5; d0u.x = q0 ? pkbf(dv0.x, dv0.y) : 0u;
  uint4 d1u = c5; d1u.x = q0 ? pkbf(dv1.x, dv1.y) : 0u;
  bf16x8 af5cur[2];
  af5cur[0] = __builtin_bit_cast(bf16x8, d0u);
  af5cur[1] = __builtin_bit_cast(bf16x8, d1u);

  float cum[2][4] = {{0.f,0.f,0.f,0.f},{0.f,0.f,0.f,0.f}};
  if (jq == 1 && cc < 2){
    #pragma unroll
    for (int G = 0; G < 2; ++G)
      #pragma unroll
      for (int r = 0; r < 4; ++r)
        cum[G][r] = obs[(size_t)(R0 + G*16 + qd*4 + r)*(TOBS*2) + (TOBS-1)*2 + cc];
  }
  #pragma unroll
  for (int G = 0; G < 2; ++G)
    #pragma unroll
    for (int r = 0; r < 4; ++r) cst[G][r] = 0.f;
  __syncthreads();   // cl reads done; outst region now writable

  // ================= decoder: 100 steps, ONE barrier/step, NO global ops =================
  #pragma unroll 1
  for (int s = 0; s < SDEC; ++s){
    const int par = s & 1;
    bf16x8 af[2][4];
    #pragma unroll
    for (int G = 0; G < 2; ++G)
      #pragma unroll
      for (int kt = 0; kt < 4; ++kt)
        af[G][kt] = *(const bf16x8*)&sm.h[par][(G*16 + cc)*KPAD + kt*32 + qd*8];
    #pragma unroll
    for (int G = 0; G < 2; ++G)
      #pragma unroll
      for (int g = 0; g < 4; ++g)
        acc[G][g] = __builtin_amdgcn_mfma_f32_16x16x32_bf16(af5cur[G], b5x[g], zz4, 0,0,0);
    #pragma unroll
    for (int kt = 0; kt < 4; ++kt)
      #pragma unroll
      for (int G = 0; G < 2; ++G)
        #pragma unroll
        for (int g = 0; g < 4; ++g)
          acc[G][g] = __builtin_amdgcn_mfma_f32_16x16x32_bf16(af[G][kt], bfr[g][kt], acc[G][g], 0,0,0);
    af5cur[0] = af5c; af5cur[1] = af5c;

    if (jq == 1 && s > 0){   // readout h_{s-1} -> cumsum -> LDS staging (no HBM in loop!)
      #pragma unroll
      for (int G = 0; G < 2; ++G){
        f32x4 a5 = {brc, brc, brc, brc};
        #pragma unroll
        for (int kt = 0; kt < 4; ++kt)
          a5 = __builtin_amdgcn_mfma_f32_16x16x32_bf16(af[G][kt],
                 __builtin_bit_cast(bf16x8, sm.b5f[lane][kt]), a5, 0,0,0);
        if (cc < 2){
          #pragma unroll
          for (int r = 0; r < 4; ++r){
            cum[G][r] += a5[r];
            sm.u.outst[G*16 + qd*4 + r][s-1][cc] = cum[G][r];
          }
        }
      }
    }

    unsigned short* hn = &sm.h[par ^ 1][0];
    #pragma unroll
    for (int G = 0; G < 2; ++G)
      #pragma unroll
      for (int r = 0; r < 4; ++r){
        float ei = ex2(acc[G][0][r]), ef = ex2(acc[G][1][r]);
        float eg = ex2(acc[G][2][r]), eo = ex2(acc[G][3][r]);
        float a1 = 1.0f + ef, a2 = 1.0f + ei, a3 = 1.0f + eg;
        float P  = a2 * a3;
        float rD = rcpf(a1 * P);
        float N  = __builtin_fmaf(cst[G][r], P, (1.0f - eg) * a1);
        float cn = N * rD;
        cst[G][r] = cn;
        float em = ex2(cn * (-TL2E));
        float rQ = rcpf((1.0f + eo) * (1.0f + em));
        float hh = (1.0f - em) * rQ;
        hn[(G*16 + qd*4 + r)*KPAD + colj] = bfs(hh);
      }
    __syncthreads();
  }

  // epilogue: pred[S-1] from h[0] -> staging
  if (jq == 1){
    #pragma unroll
    for (int G = 0; G < 2; ++G){
      bf16x8 af[4];
      #pragma unroll
      for (int kt = 0; kt < 4; ++kt)
        af[kt] = *(const bf16x8*)&sm.h[0][(G*16 + cc)*KPAD + kt*32 + qd*8];
      f32x4 a5 = {brc, brc, brc, brc};
      #pragma unroll
      for (int kt = 0; kt < 4; ++kt)
        a5 = __builtin_amdgcn_mfma_f32_16x16x32_bf16(af[kt],
               __builtin_bit_cast(bf16x8, sm.b5f[lane][kt]), a5, 0,0,0);
      if (cc < 2){
        #pragma unroll
        for (int r = 0; r < 4; ++r)
          sm.u.outst[G*16 + qd*4 + r][SDEC-1][cc] = cum[G][r] + a5[r];
      }
    }
  }
  __syncthreads();

  // bulk write: LDS staging -> HBM, fully coalesced float2
  {
    const float2* src = (const float2*)&sm.u.outst[0][0][0];
    float2* dst = (float2*)(out + (size_t)R0 * SDEC * 2);
    for (int i = tid; i < ROWS * SDEC; i += 512)
      dst[i] = src[i];
  }
}

extern "C" void kernel_launch(void* const* d_in, const int* in_sizes, int n_in,
                              void* d_out, int out_size, void* d_ws, size_t ws_size,
                              hipStream_t stream) {
  (void)in_sizes; (void)n_in; (void)d_ws; (void)ws_size; (void)out_size;
  const float* obs   = (const float*)d_in[0];
  // d_in[1] = num_steps (100), compile-time constant here
  const float* We    = (const float*)d_in[2];
  const float* be    = (const float*)d_in[3];
  const float* Wih_e = (const float*)d_in[4];
  const float* Whh_e = (const float*)d_in[5];
  const float* b_e   = (const float*)d_in[6];
  const float* Wm1   = (const float*)d_in[7];
  const float* bm1   = (const float*)d_in[8];
  const float* Wm2   = (const float*)d_in[9];
  const float* bm2   = (const float*)d_in[10];
  const float* Wd    = (const float*)d_in[11];
  const float* bd    = (const float*)d_in[12];
  const float* Wih_d = (const float*)d_in[13];
  const float* Whh_d = (const float*)d_in[14];
  const float* b_d   = (const float*)d_in[15];
  const float* Wr    = (const float*)d_in[16];
  const float* br    = (const float*)d_in[17];
  const float* zz    = (const float*)d_in[18];
  hipLaunchKernelGGL(seqgen, dim3(8192 / ROWS), dim3(512), 0, stream,
                     obs, We, be, Wih_e, Whh_e, b_e, Wm1, bm1, Wm2, bm2,
                     Wd, bd, Wih_d, Whh_d, b_d, Wr, br, zz, (float*)d_out);
}

// Round 8
// 322.547 us; speedup vs baseline: 1.6696x; 1.0634x over previous
//
#include <hip/hip_runtime.h>

#define TOBS  50
#define SDEC  100
#define HID   128
#define EMB   64
#define MD    256
#define M2N   112
#define NZ    16
#define ROWS  32
#define KPAD  140           // shorts; 70-dw row stride (R2/R7-proven low-conflict)
#define H1PAD 268
#define L2E   1.4426950408889634f
#define TL2E  2.8853900817779268f

using bf16x8 = __attribute__((ext_vector_type(8))) short;
using f32x4  = __attribute__((ext_vector_type(4))) float;

struct alignas(16) SMem {
  unsigned short h[2][ROWS * KPAD];      // 17920 B  h double buffer (bf16)
  unsigned int offsb[TOBS][ROWS];        //  6400 B  encoder offsets (bf16x2)
  union {
    float4 cl[512];                      //  8192 B  fused input consts
    unsigned short h1[ROWS * H1PAD];     // 17152 B  MLP hidden
    float outst[ROWS][SDEC][2];          // 25600 B  decoder output staging
  } u;
  uint4 b5f[64][5];                      //  5120 B  readout Wr frags (stride 5)
  float offlast[ROWS][2];
  float delta[ROWS][2];
};

__device__ __forceinline__ unsigned int rnd16(float x){
  return __builtin_bit_cast(unsigned int, x) + 0x8000u;
}
__device__ __forceinline__ unsigned int pkbf(float a, float b){
  return __builtin_amdgcn_perm(rnd16(b), rnd16(a), 0x07060302u);
}
__device__ __forceinline__ unsigned short bfs(float x){ return (unsigned short)(rnd16(x) >> 16); }
__device__ __forceinline__ float rcpf(float x){ return __builtin_amdgcn_rcpf(x); }
__device__ __forceinline__ float ex2(float x){ return __builtin_amdgcn_exp2f(x); }
__device__ __forceinline__ bf16x8 pack8s(const float* p, float s){
  float4 a = *(const float4*)(p);
  float4 b = *(const float4*)(p + 4);
  uint4 u;
  u.x = pkbf(s*a.x, s*a.y); u.y = pkbf(s*a.z, s*a.w);
  u.z = pkbf(s*b.x, s*b.y); u.w = pkbf(s*b.z, s*b.w);
  return __builtin_bit_cast(bf16x8, u);
}
__device__ __forceinline__ bf16x8 pack8(const float* p){ return pack8s(p, 1.0f); }

// one LSTM output row-chunk: consumes acc[G][0..3][R], updates cst[G][R], writes h
#define ELEM_R(G, R) do { \
  float ei_ = ex2(acc[G][0][R]), ef_ = ex2(acc[G][1][R]); \
  float eg_ = ex2(acc[G][2][R]), eo_ = ex2(acc[G][3][R]); \
  float a1_ = 1.0f + ef_, a2_ = 1.0f + ei_, a3_ = 1.0f + eg_; \
  float P_  = a2_ * a3_; \
  float rD_ = rcpf(a1_ * P_); \
  float N_  = __builtin_fmaf(cst[G][R], P_, (1.0f - eg_) * a1_); \
  float cn_ = N_ * rD_; \
  cst[G][R] = cn_; \
  float em_ = ex2(cn_ * (-TL2E)); \
  float rQ_ = rcpf((1.0f + eo_) * (1.0f + em_)); \
  float hh_ = (1.0f - em_) * rQ_; \
  hn[((G)*16 + qd*4 + (R))*KPAD + colj] = bfs(hh_); \
} while(0)

extern "C" __global__ void __launch_bounds__(512, 2)
seqgen(const float* __restrict__ obs,
       const float* __restrict__ We,    const float* __restrict__ be,
       const float* __restrict__ Wih_e, const float* __restrict__ Whh_e, const float* __restrict__ b_e,
       const float* __restrict__ Wm1,   const float* __restrict__ bm1,
       const float* __restrict__ Wm2,   const float* __restrict__ bm2,
       const float* __restrict__ Wd,    const float* __restrict__ bd,
       const float* __restrict__ Wih_d, const float* __restrict__ Whh_d, const float* __restrict__ b_d,
       const float* __restrict__ Wr,    const float* __restrict__ br,
       const float* __restrict__ z,     float* __restrict__ out)
{
  __shared__ SMem sm;
  const int tid  = threadIdx.x;
  const int lane = tid & 63;
  const int jq   = tid >> 6;        // wave = 16-col tile (0..7)
  const int cc   = lane & 15;
  const int qd   = lane >> 4;
  const bool q0  = (qd == 0);
  const int R0   = blockIdx.x * ROWS;
  const int colj = jq * 16 + cc;
  const unsigned int one_q0 = q0 ? 0x3F80u : 0u;
  const float sg4[4] = {-L2E, -L2E, -TL2E, -L2E};   // exp2 scale folded per gate

  // ---------------- prep ----------------
  for (int i = tid; i < TOBS * ROWS; i += 512){
    int t = i >> 5, row = i & 31;
    const float* ob = obs + (size_t)(R0 + row) * (TOBS * 2) + t * 2;
    float o0 = ob[0], o1 = ob[1];
    if (t){ o0 -= ob[-2]; o1 -= ob[-1]; }
    sm.offsb[t][row] = pkbf(o0, o1);
    if (t == TOBS - 1){ sm.offlast[row][0] = o0; sm.offlast[row][1] = o1; }
  }
  for (int i = tid; i < ROWS * KPAD / 2; i += 512)
    ((unsigned int*)&sm.h[0][0])[i] = 0u;
  {
    const float* wr = Wih_e + tid * EMB;
    float w0 = 0.f, w1 = 0.f, bb = b_e[tid];
    for (int e = 0; e < EMB; ++e){
      float w = wr[e];
      w0 += w * We[e*2]; w1 += w * We[e*2+1]; bb += w * be[e];
    }
    sm.u.cl[tid] = make_float4(bb, w0, w1, 0.f);
  }
  __syncthreads();

  // input/bias B-frags {s*w0, s*w1, s*bc} at k=0,1,2 (qd==0 lanes)
  bf16x8 b5x[4];
  #pragma unroll
  for (int g = 0; g < 4; ++g){
    float4 v = sm.u.cl[g*128 + colj];
    float s = sg4[g];
    uint4 w;
    w.x = q0 ? pkbf(s*v.y, s*v.z) : 0u;
    w.y = q0 ? (rnd16(s*v.x) >> 16) : 0u;
    w.z = 0u; w.w = 0u;
    b5x[g] = __builtin_bit_cast(bf16x8, w);
  }
  // encoder Whh in registers, pre-scaled per gate
  bf16x8 bfr[4][4];
  #pragma unroll
  for (int kt = 0; kt < 4; ++kt)
    #pragma unroll
    for (int g = 0; g < 4; ++g)
      bfr[g][kt] = pack8s(Whh_e + (size_t)(g*128 + colj) * HID + kt*32 + qd*8, sg4[g]);

  const f32x4 zz4 = {0.f, 0.f, 0.f, 0.f};
  f32x4 acc[2][4];
  float cst[2][4];
  #pragma unroll
  for (int G = 0; G < 2; ++G)
    #pragma unroll
    for (int r = 0; r < 4; ++r) cst[G][r] = 0.f;

  // ================= encoder: 50 steps, ONE barrier/step =================
  // structure: G0 MFMA chain -> [G1 MFMA chain interleaved with G0 ELEM] -> G1 ELEM
  #pragma unroll 1
  for (int t = 0; t < TOBS; ++t){
    const int par = t & 1;
    bf16x8 af0[4], af1[4];
    #pragma unroll
    for (int kt = 0; kt < 4; ++kt)
      af0[kt] = *(const bf16x8*)&sm.h[par][cc*KPAD + kt*32 + qd*8];
    unsigned int po0 = sm.offsb[t][cc];
    unsigned int po1 = sm.offsb[t][16 + cc];
    {
      uint4 a5i; a5i.x = q0 ? po0 : 0u; a5i.y = one_q0; a5i.z = 0u; a5i.w = 0u;
      bf16x8 af5 = __builtin_bit_cast(bf16x8, a5i);
      #pragma unroll
      for (int g = 0; g < 4; ++g)
        acc[0][g] = __builtin_amdgcn_mfma_f32_16x16x32_bf16(af5, b5x[g], zz4, 0,0,0);
    }
    #pragma unroll
    for (int kt = 0; kt < 4; ++kt)
      #pragma unroll
      for (int g = 0; g < 4; ++g)
        acc[0][g] = __builtin_amdgcn_mfma_f32_16x16x32_bf16(af0[kt], bfr[g][kt], acc[0][g], 0,0,0);
    #pragma unroll
    for (int kt = 0; kt < 4; ++kt)
      af1[kt] = *(const bf16x8*)&sm.h[par][(16 + cc)*KPAD + kt*32 + qd*8];
    {
      uint4 a5i; a5i.x = q0 ? po1 : 0u; a5i.y = one_q0; a5i.z = 0u; a5i.w = 0u;
      bf16x8 af5 = __builtin_bit_cast(bf16x8, a5i);
      #pragma unroll
      for (int g = 0; g < 4; ++g)
        acc[1][g] = __builtin_amdgcn_mfma_f32_16x16x32_bf16(af5, b5x[g], zz4, 0,0,0);
    }
    unsigned short* hn = &sm.h[par ^ 1][0];
    // interleave: 4 G1-MFMAs then one G0 ELEM row per kt
    #pragma unroll
    for (int g = 0; g < 4; ++g)
      acc[1][g] = __builtin_amdgcn_mfma_f32_16x16x32_bf16(af1[0], bfr[g][0], acc[1][g], 0,0,0);
    ELEM_R(0, 0);
    #pragma unroll
    for (int g = 0; g < 4; ++g)
      acc[1][g] = __builtin_amdgcn_mfma_f32_16x16x32_bf16(af1[1], bfr[g][1], acc[1][g], 0,0,0);
    ELEM_R(0, 1);
    #pragma unroll
    for (int g = 0; g < 4; ++g)
      acc[1][g] = __builtin_amdgcn_mfma_f32_16x16x32_bf16(af1[2], bfr[g][2], acc[1][g], 0,0,0);
    ELEM_R(0, 2);
    #pragma unroll
    for (int g = 0; g < 4; ++g)
      acc[1][g] = __builtin_amdgcn_mfma_f32_16x16x32_bf16(af1[3], bfr[g][3], acc[1][g], 0,0,0);
    ELEM_R(0, 3);
    ELEM_R(1, 0); ELEM_R(1, 1); ELEM_R(1, 2); ELEM_R(1, 3);
    __syncthreads();
  }
  // hF in sm.h[0]

  // ================= MLP =================
  {
    bf16x8 af[2][4];
    #pragma unroll
    for (int G = 0; G < 2; ++G)
      #pragma unroll
      for (int kt = 0; kt < 4; ++kt)
        af[G][kt] = *(const bf16x8*)&sm.h[0][(G*16 + cc)*KPAD + kt*32 + qd*8];
    f32x4 a1[2][2];
    #pragma unroll
    for (int t2 = 0; t2 < 2; ++t2){
      const int n = jq*32 + t2*16 + cc;
      float b = bm1[n];
      #pragma unroll
      for (int G = 0; G < 2; ++G){ a1[t2][G][0]=b; a1[t2][G][1]=b; a1[t2][G][2]=b; a1[t2][G][3]=b; }
      #pragma unroll
      for (int kt = 0; kt < 4; ++kt){
        bf16x8 wb = pack8(Wm1 + (size_t)n * HID + kt*32 + qd*8);
        a1[t2][0] = __builtin_amdgcn_mfma_f32_16x16x32_bf16(af[0][kt], wb, a1[t2][0], 0,0,0);
        a1[t2][1] = __builtin_amdgcn_mfma_f32_16x16x32_bf16(af[1][kt], wb, a1[t2][1], 0,0,0);
      }
    }
    __syncthreads();
    #pragma unroll
    for (int t2 = 0; t2 < 2; ++t2)
      #pragma unroll
      for (int G = 0; G < 2; ++G)
        #pragma unroll
        for (int r = 0; r < 4; ++r){
          float v = a1[t2][G][r]; v = v > 0.f ? v : 0.f;
          sm.u.h1[(G*16 + qd*4 + r)*H1PAD + jq*32 + t2*16 + cc] = bfs(v);
        }
  }
  __syncthreads();
  {
    bf16x8 af2[2][8];
    #pragma unroll
    for (int G = 0; G < 2; ++G)
      #pragma unroll
      for (int kt = 0; kt < 8; ++kt)
        af2[G][kt] = *(const bf16x8*)&sm.u.h1[(G*16 + cc)*H1PAD + kt*32 + qd*8];
    if (jq < 7){
      const int n2 = jq*16 + cc;
      float b = bm2[n2];
      f32x4 a2[2];
      #pragma unroll
      for (int G = 0; G < 2; ++G){ a2[G][0]=b; a2[G][1]=b; a2[G][2]=b; a2[G][3]=b; }
      #pragma unroll
      for (int kt = 0; kt < 8; ++kt){
        bf16x8 wb = pack8(Wm2 + (size_t)n2 * MD + kt*32 + qd*8);
        a2[0] = __builtin_amdgcn_mfma_f32_16x16x32_bf16(af2[0][kt], wb, a2[0], 0,0,0);
        a2[1] = __builtin_amdgcn_mfma_f32_16x16x32_bf16(af2[1][kt], wb, a2[1], 0,0,0);
      }
      #pragma unroll
      for (int G = 0; G < 2; ++G)
        #pragma unroll
        for (int r = 0; r < 4; ++r){
          float v = a2[G][r]; v = v > 0.f ? v : 0.f;
          sm.h[0][(G*16 + qd*4 + r)*KPAD + jq*16 + cc] = bfs(v);
        }
    }
    {
      int row = tid >> 4, nz = tid & 15;
      sm.h[0][row*KPAD + M2N + nz] = bfs(z[(size_t)(R0 + row)*NZ + nz]);
    }
  }
  __syncthreads();   // dh complete in h[0]

  // ================= decoder prep =================
  {
    const float* wr = Wih_d + tid * EMB;
    float w0 = 0.f, w1 = 0.f, bb = b_d[tid];
    for (int e = 0; e < EMB; ++e){
      float w = wr[e];
      w0 += w * Wd[e*2]; w1 += w * Wd[e*2+1]; bb += w * bd[e];
    }
    sm.u.cl[tid] = make_float4(bb, w0, w1, 0.f);
  }
  const float br0 = br[0], br1 = br[1];
  const float brc = (cc == 0) ? br0 : br1;
  if (jq == 1){   // readout Wr fragments + step-0 delta (one-time)
    uint4 bq[4];
    #pragma unroll
    for (int kt = 0; kt < 4; ++kt){
      bf16x8 f = pack8(Wr + (size_t)(cc & 1)*HID + kt*32 + qd*8);
      uint4 uu = __builtin_bit_cast(uint4, f);
      if (cc >= 2){ uu.x = 0u; uu.y = 0u; uu.z = 0u; uu.w = 0u; }
      bq[kt] = uu;
      sm.b5f[lane][kt] = uu;
    }
    #pragma unroll
    for (int G = 0; G < 2; ++G){
      bf16x8 afd[4];
      #pragma unroll
      for (int kt = 0; kt < 4; ++kt)
        afd[kt] = *(const bf16x8*)&sm.h[0][(G*16 + cc)*KPAD + kt*32 + qd*8];
      f32x4 a5 = zz4;
      #pragma unroll
      for (int kt = 0; kt < 4; ++kt)
        a5 = __builtin_amdgcn_mfma_f32_16x16x32_bf16(afd[kt], __builtin_bit_cast(bf16x8, bq[kt]), a5, 0,0,0);
      if (cc < 2){
        #pragma unroll
        for (int r = 0; r < 4; ++r){
          int row = G*16 + qd*4 + r;
          sm.delta[row][cc] = sm.offlast[row][cc] - (a5[r] + brc);
        }
      }
    }
  }
  __syncthreads();

  // feedback-folded decoder consts (pre-scaled): bfr' = s_g*(Whh_d + u0(x)Wr0 + u1(x)Wr1)
  float w0g[4], w1g[4];
  f32x4 civ[4];                 // steady-state C-init: splat(s_g * bc'_g)
  #pragma unroll
  for (int g = 0; g < 4; ++g){
    float4 v = sm.u.cl[g*128 + colj];
    w0g[g] = v.y; w1g[g] = v.z;
    float s = sg4[g];
    float bcp = v.x + v.y*br0 + v.z*br1;
    float ci = s * bcp;
    civ[g][0] = ci; civ[g][1] = ci; civ[g][2] = ci; civ[g][3] = ci;
    uint4 w;
    w.x = q0 ? pkbf(s*v.y, s*v.z) : 0u;
    w.y = q0 ? (rnd16(s*bcp) >> 16) : 0u;
    w.z = 0u; w.w = 0u;
    b5x[g] = __builtin_bit_cast(bf16x8, w);
  }
  #pragma unroll
  for (int kt = 0; kt < 4; ++kt){
    const int kb = kt*32 + qd*8;
    float4 wa = *(const float4*)(Wr + kb),       wb2 = *(const float4*)(Wr + kb + 4);
    float4 va = *(const float4*)(Wr + HID + kb), vb2 = *(const float4*)(Wr + HID + kb + 4);
    #pragma unroll
    for (int g = 0; g < 4; ++g){
      const float* pp = Whh_d + (size_t)(g*128 + colj) * HID + kb;
      float4 fa = *(const float4*)pp, fb = *(const float4*)(pp + 4);
      float s = sg4[g];
      uint4 uu;
      uu.x = pkbf(s*(fa.x + w0g[g]*wa.x  + w1g[g]*va.x),  s*(fa.y + w0g[g]*wa.y  + w1g[g]*va.y));
      uu.y = pkbf(s*(fa.z + w0g[g]*wa.z  + w1g[g]*va.z),  s*(fa.w + w0g[g]*wa.w  + w1g[g]*va.w));
      uu.z = pkbf(s*(fb.x + w0g[g]*wb2.x + w1g[g]*vb2.x), s*(fb.y + w0g[g]*wb2.y + w1g[g]*vb2.y));
      uu.w = pkbf(s*(fb.z + w0g[g]*wb2.z + w1g[g]*vb2.z), s*(fb.w + w0g[g]*wb2.w + w1g[g]*vb2.w));
      bfr[g][kt] = __builtin_bit_cast(bf16x8, uu);
    }
  }
  // step-0 delta A-frags
  uint4 c5; c5.x = 0u; c5.y = one_q0; c5.z = 0u; c5.w = 0u;
  float2 dv0 = *(const float2*)&sm.delta[cc][0];
  float2 dv1 = *(const float2*)&sm.delta[16 + cc][0];
  uint4 d0u = c5; d0u.x = q0 ? pkbf(dv0.x, dv0.y) : 0u;
  uint4 d1u = c5; d1u.x = q0 ? pkbf(dv1.x, dv1.y) : 0u;
  const bf16x8 af5d0 = __builtin_bit_cast(bf16x8, d0u);
  const bf16x8 af5d1 = __builtin_bit_cast(bf16x8, d1u);

  // readout ownership: jq==1 -> G0 rows, jq==3 -> G1 rows
  const int Gown = (jq == 3) ? 1 : 0;
  float cum[4] = {0.f,0.f,0.f,0.f};
  if ((jq == 1 || jq == 3) && cc < 2){
    #pragma unroll
    for (int r = 0; r < 4; ++r)
      cum[r] = obs[(size_t)(R0 + Gown*16 + qd*4 + r)*(TOBS*2) + (TOBS-1)*2 + cc];
  }
  #pragma unroll
  for (int G = 0; G < 2; ++G)
    #pragma unroll
    for (int r = 0; r < 4; ++r) cst[G][r] = 0.f;
  __syncthreads();   // cl reads done; outst region now writable

  // ================= decoder: 100 steps, ONE barrier/step, NO global ops =================
  #pragma unroll 1
  for (int s = 0; s < SDEC; ++s){
    const int par = s & 1;
    bf16x8 af0[4], af1[4];
    #pragma unroll
    for (int kt = 0; kt < 4; ++kt)
      af0[kt] = *(const bf16x8*)&sm.h[par][cc*KPAD + kt*32 + qd*8];
    // G0 chain (kt0 carries the C-init; s==0 adds the delta-MFMA)
    if (s == 0){
      #pragma unroll
      for (int g = 0; g < 4; ++g){
        acc[0][g] = __builtin_amdgcn_mfma_f32_16x16x32_bf16(af5d0, b5x[g], zz4, 0,0,0);
        acc[0][g] = __builtin_amdgcn_mfma_f32_16x16x32_bf16(af0[0], bfr[g][0], acc[0][g], 0,0,0);
      }
    } else {
      #pragma unroll
      for (int g = 0; g < 4; ++g)
        acc[0][g] = __builtin_amdgcn_mfma_f32_16x16x32_bf16(af0[0], bfr[g][0], civ[g], 0,0,0);
    }
    #pragma unroll
    for (int kt = 1; kt < 4; ++kt)
      #pragma unroll
      for (int g = 0; g < 4; ++g)
        acc[0][g] = __builtin_amdgcn_mfma_f32_16x16x32_bf16(af0[kt], bfr[g][kt], acc[0][g], 0,0,0);
    #pragma unroll
    for (int kt = 0; kt < 4; ++kt)
      af1[kt] = *(const bf16x8*)&sm.h[par][(16 + cc)*KPAD + kt*32 + qd*8];
    // readout G0 (wave jq==1 only)
    if (jq == 1 && s > 0){
      f32x4 a5 = {brc, brc, brc, brc};
      #pragma unroll
      for (int kt = 0; kt < 4; ++kt)
        a5 = __builtin_amdgcn_mfma_f32_16x16x32_bf16(af0[kt],
               __builtin_bit_cast(bf16x8, sm.b5f[lane][kt]), a5, 0,0,0);
      if (cc < 2){
        #pragma unroll
        for (int r = 0; r < 4; ++r){
          cum[r] += a5[r];
          sm.u.outst[qd*4 + r][s-1][cc] = cum[r];
        }
      }
    }
    // G1 chain interleaved with G0 ELEM
    if (s == 0){
      #pragma unroll
      for (int g = 0; g < 4; ++g){
        acc[1][g] = __builtin_amdgcn_mfma_f32_16x16x32_bf16(af5d1, b5x[g], zz4, 0,0,0);
        acc[1][g] = __builtin_amdgcn_mfma_f32_16x16x32_bf16(af1[0], bfr[g][0], acc[1][g], 0,0,0);
      }
    } else {
      #pragma unroll
      for (int g = 0; g < 4; ++g)
        acc[1][g] = __builtin_amdgcn_mfma_f32_16x16x32_bf16(af1[0], bfr[g][0], civ[g], 0,0,0);
    }
    unsigned short* hn = &sm.h[par ^ 1][0];
    ELEM_R(0, 0);
    #pragma unroll
    for (int g = 0; g < 4; ++g)
      acc[1][g] = __builtin_amdgcn_mfma_f32_16x16x32_bf16(af1[1], bfr[g][1], acc[1][g], 0,0,0);
    ELEM_R(0, 1);
    #pragma unroll
    for (int g = 0; g < 4; ++g)
      acc[1][g] = __builtin_amdgcn_mfma_f32_16x16x32_bf16(af1[2], bfr[g][2], acc[1][g], 0,0,0);
    ELEM_R(0, 2);
    #pragma unroll
    for (int g = 0; g < 4; ++g)
      acc[1][g] = __builtin_amdgcn_mfma_f32_16x16x32_bf16(af1[3], bfr[g][3], acc[1][g], 0,0,0);
    ELEM_R(0, 3);
    // readout G1 (wave jq==3 only) — matrix work overlapping others' ELEM
    if (jq == 3 && s > 0){
      f32x4 a5 = {brc, brc, brc, brc};
      #pragma unroll
      for (int kt = 0; kt < 4; ++kt)
        a5 = __builtin_amdgcn_mfma_f32_16x16x32_bf16(af1[kt],
               __builtin_bit_cast(bf16x8, sm.b5f[lane][kt]), a5, 0,0,0);
      if (cc < 2){
        #pragma unroll
        for (int r = 0; r < 4; ++r){
          cum[r] += a5[r];
          sm.u.outst[16 + qd*4 + r][s-1][cc] = cum[r];
        }
      }
    }
    ELEM_R(1, 0); ELEM_R(1, 1); ELEM_R(1, 2); ELEM_R(1, 3);
    __syncthreads();
  }

  // epilogue: pred[S-1] from h[0] (= h_{S-1}); split across jq==1 / jq==3
  if (jq == 1 || jq == 3){
    bf16x8 af[4];
    #pragma unroll
    for (int kt = 0; kt < 4; ++kt)
      af[kt] = *(const bf16x8*)&sm.h[0][(Gown*16 + cc)*KPAD + kt*32 + qd*8];
    f32x4 a5 = {brc, brc, brc, brc};
    #pragma unroll
    for (int kt = 0; kt < 4; ++kt)
      a5 = __builtin_amdgcn_mfma_f32_16x16x32_bf16(af[kt],
             __builtin_bit_cast(bf16x8, sm.b5f[lane][kt]), a5, 0,0,0);
    if (cc < 2){
      #pragma unroll
      for (int r = 0; r < 4; ++r)
        sm.u.outst[Gown*16 + qd*4 + r][SDEC-1][cc] = cum[r] + a5[r];
    }
  }
  __syncthreads();

  // bulk write: LDS staging -> HBM, fully coalesced float2
  {
    const float2* src = (const float2*)&sm.u.outst[0][0][0];
    float2* dst = (float2*)(out + (size_t)R0 * SDEC * 2);
    for (int i = tid; i < ROWS * SDEC; i += 512)
      dst[i] = src[i];
  }
}

extern "C" void kernel_launch(void* const* d_in, const int* in_sizes, int n_in,
                              void* d_out, int out_size, void* d_ws, size_t ws_size,
                              hipStream_t stream) {
  (void)in_sizes; (void)n_in; (void)d_ws; (void)ws_size; (void)out_size;
  const float* obs   = (const float*)d_in[0];
  // d_in[1] = num_steps (100), compile-time constant here
  const float* We    = (const float*)d_in[2];
  const float* be    = (const float*)d_in[3];
  const float* Wih_e = (const float*)d_in[4];
  const float* Whh_e = (const float*)d_in[5];
  const float* b_e   = (const float*)d_in[6];
  const float* Wm1   = (const float*)d_in[7];
  const float* bm1   = (const float*)d_in[8];
  const float* Wm2   = (const float*)d_in[9];
  const float* bm2   = (const float*)d_in[10];
  const float* Wd    = (const float*)d_in[11];
  const float* bd    = (const float*)d_in[12];
  const float* Wih_d = (const float*)d_in[13];
  const float* Whh_d = (const float*)d_in[14];
  const float* b_d   = (const float*)d_in[15];
  const float* Wr    = (const float*)d_in[16];
  const float* br    = (const float*)d_in[17];
  const float* zz    = (const float*)d_in[18];
  hipLaunchKernelGGL(seqgen, dim3(8192 / ROWS), dim3(512), 0, stream,
                     obs, We, be, Wih_e, Whh_e, b_e, Wm1, bm1, Wm2, bm2,
                     Wd, bd, Wih_d, Whh_d, b_d, Wr, br, zz, (float*)d_out);
}